// Round 8
// baseline (652.976 us; speedup 1.0000x reference)
//
#include <hip/hip_runtime.h>
#include <hip/hip_cooperative_groups.h>

namespace cg = cooperative_groups;

// scatter-mean, fully fused (cooperative kernel, grid.sync between phases):
//   src: [E, 64] f32, idx: [E] int32, out: [N, 64] f32.
// ws layout (u32): cnt[N] | ovf_cnt+list | slot[N*CAP]
// CAP=32 (E/N=16 avg, Poisson: P(cnt>32)~3e-5/seg -> handful of overflow EDGES,
// handled exactly in phase 3). Slot table 6.4 MB -> L2-friendly.

typedef unsigned int u32;

#define CAP 32
#define OVF_MAX 32768

__global__ __launch_bounds__(256, 4)
void fused_scatter_mean_kernel(const float4* __restrict__ src4,
                               const int* __restrict__ idx,
                               u32* __restrict__ cnt,
                               u32* __restrict__ ovf,
                               u32* __restrict__ slot,
                               float4* __restrict__ out4,
                               int E, int N)
{
    cg::grid_group grid = cg::this_grid();
    const int tid = blockIdx.x * blockDim.x + threadIdx.x;
    const int nthreads = gridDim.x * blockDim.x;

    // ---- phase 0: zero cnt[N] + ovf counter ----
    for (int i = tid; i <= N; i += nthreads) {
        if (i < N) cnt[i] = 0u; else ovf[0] = 0u;
    }
    grid.sync();

    // ---- phase 1: slot scatter (only atomics in the pipeline) ----
    for (int i = tid; i < E; i += nthreads) {
        int n = idx[i];
        u32 pos = atomicAdd(&cnt[n], 1u);
        if (pos < CAP) {
            slot[(long)n * CAP + pos] = (u32)i;
        } else {
            u32 o = atomicAdd(&ovf[0], 1u);
            if (o < OVF_MAX) ovf[1 + o] = (u32)i;
        }
    }
    grid.sync();

    // ---- phase 2: gather. one wave per segment, 2-stage (cnt,slot) prefetch.
    // lane layout: g = lane>>4 row-group, q = lane&15 column-quad (float4).
    const int lane = threadIdx.x & 63;
    const int g = lane >> 4;
    const int q = lane & 15;
    const int wave = tid >> 6;
    const int nwaves = nthreads >> 6;

    int s = wave;
    u32 c = 0, my = 0;
    if (s < N) {
        c = cnt[s];
        my = (lane < CAP) ? slot[(long)s * CAP + lane] : 0u;
    }
    while (s < N) {
        int s2 = s + nwaves;
        u32 c2 = 0, my2 = 0;
        if (s2 < N) {                      // issue next segment's loads early;
            c2 = cnt[s2];                  // they overlap the src loads below
            my2 = (lane < CAP) ? slot[(long)s2 * CAP + lane] : 0u;
        }
        int m = (int)(c < CAP ? c : CAP);
        float4 acc = make_float4(0.f, 0.f, 0.f, 0.f);
        int k = 0;
        for (; k + 8 <= m; k += 8) {       // 8 rows/iter: 2 independent float4 loads
            u32 eA = __shfl(my, k + g);
            u32 eB = __shfl(my, k + 4 + g);
            float4 vA = src4[(long)eA * 16 + q];
            float4 vB = src4[(long)eB * 16 + q];
            acc.x += vA.x + vB.x; acc.y += vA.y + vB.y;
            acc.z += vA.z + vB.z; acc.w += vA.w + vB.w;
        }
        for (; k < m; k += 4) {            // masked tail, 4 rows at a time
            int r = k + g;
            u32 e = __shfl(my, r < m ? r : k);
            if (r < m) {
                float4 v = src4[(long)e * 16 + q];
                acc.x += v.x; acc.y += v.y; acc.z += v.z; acc.w += v.w;
            }
        }
        // reduce across the 4 row-groups (lanes q, q+16, q+32, q+48)
        acc.x += __shfl_down(acc.x, 32); acc.y += __shfl_down(acc.y, 32);
        acc.z += __shfl_down(acc.z, 32); acc.w += __shfl_down(acc.w, 32);
        acc.x += __shfl_down(acc.x, 16); acc.y += __shfl_down(acc.y, 16);
        acc.z += __shfl_down(acc.z, 16); acc.w += __shfl_down(acc.w, 16);
        if (g == 0) {
            float inv = 1.0f / (float)(c > 1u ? c : 1u);
            out4[(long)s * 16 + q] = make_float4(acc.x * inv, acc.y * inv,
                                                 acc.z * inv, acc.w * inv);
        }
        s = s2; c = c2; my = my2;
    }
    grid.sync();

    // ---- phase 3: overflow fixup (normally 0 entries) ----
    const float* src = (const float*)src4;
    float* out = (float*)out4;
    u32 no = ovf[0]; if (no > OVF_MAX) no = OVF_MAX;
    for (u32 t = (u32)wave; t < no; t += (u32)nwaves) {
        u32 e = ovf[1 + t];
        int n = idx[e];
        u32 cc = cnt[n];
        float inv = 1.0f / (float)(cc > 1u ? cc : 1u);
        atomicAdd(&out[(long)n * 64 + lane], src[(long)e * 64 + lane] * inv);
    }
}

// ---------- non-cooperative fallback: round-7 slot pipeline ----------
__global__ void zero_u32_kernel(u32* __restrict__ p, int n) {
    int i = blockIdx.x * blockDim.x + threadIdx.x;
    int stride = gridDim.x * blockDim.x;
    for (; i < n; i += stride) p[i] = 0u;
}

__global__ void slot_scatter_kernel(const int* __restrict__ idx, u32* __restrict__ cnt,
                                    u32* __restrict__ slot, u32* __restrict__ ovf, int E) {
    int i = blockIdx.x * blockDim.x + threadIdx.x;
    int stride = gridDim.x * blockDim.x;
    for (; i < E; i += stride) {
        int n = idx[i];
        u32 pos = atomicAdd(&cnt[n], 1u);
        if (pos < CAP) slot[(long)n * CAP + pos] = (u32)i;
        else { u32 o = atomicAdd(&ovf[0], 1u); if (o < OVF_MAX) ovf[1 + o] = (u32)i; }
    }
}

__global__ void gather_mean_kernel(const float4* __restrict__ src4, const u32* __restrict__ slot,
                                   const u32* __restrict__ cnt, float4* __restrict__ out4, int N) {
    int seg = blockIdx.x * (blockDim.x >> 6) + (threadIdx.x >> 6);
    if (seg >= N) return;
    int lane = threadIdx.x & 63;
    int g = lane >> 4, q = lane & 15;
    int c = (int)cnt[seg];
    int m = c < CAP ? c : CAP;
    const u32* sl = slot + (long)seg * CAP;
    u32 my = (lane < CAP) ? sl[lane] : 0u;
    float4 acc = make_float4(0.f, 0.f, 0.f, 0.f);
    int k = 0;
    for (; k + 8 <= m; k += 8) {
        u32 eA = __shfl(my, k + g);
        u32 eB = __shfl(my, k + 4 + g);
        float4 vA = src4[(long)eA * 16 + q];
        float4 vB = src4[(long)eB * 16 + q];
        acc.x += vA.x + vB.x; acc.y += vA.y + vB.y;
        acc.z += vA.z + vB.z; acc.w += vA.w + vB.w;
    }
    for (; k < m; k += 4) {
        int r = k + g;
        u32 e = __shfl(my, r < m ? r : k);
        if (r < m) {
            float4 v = src4[(long)e * 16 + q];
            acc.x += v.x; acc.y += v.y; acc.z += v.z; acc.w += v.w;
        }
    }
    acc.x += __shfl_down(acc.x, 32); acc.y += __shfl_down(acc.y, 32);
    acc.z += __shfl_down(acc.z, 32); acc.w += __shfl_down(acc.w, 32);
    acc.x += __shfl_down(acc.x, 16); acc.y += __shfl_down(acc.y, 16);
    acc.z += __shfl_down(acc.z, 16); acc.w += __shfl_down(acc.w, 16);
    if (g == 0) {
        float inv = 1.0f / (float)(c > 1 ? c : 1);
        out4[(long)seg * 16 + q] = make_float4(acc.x * inv, acc.y * inv,
                                               acc.z * inv, acc.w * inv);
    }
}

__global__ void ovf_fix_kernel(const float* __restrict__ src, const int* __restrict__ idx,
                               const u32* __restrict__ cnt, const u32* __restrict__ ovf,
                               float* __restrict__ out) {
    u32 no = ovf[0]; if (no > OVF_MAX) no = OVF_MAX;
    int nw = (gridDim.x * blockDim.x) >> 6;
    int w  = (blockIdx.x * blockDim.x + threadIdx.x) >> 6;
    int lane = threadIdx.x & 63;
    for (u32 t = (u32)w; t < no; t += (u32)nw) {
        u32 e = ovf[1 + t];
        int n = idx[e];
        u32 c = cnt[n];
        float inv = 1.0f / (float)(c > 1u ? c : 1u);
        atomicAdd(&out[(long)n * 64 + lane], src[(long)e * 64 + lane] * inv);
    }
}

// ---------- small-ws fallback: atomic version ----------
__global__ void zero_f4_kernel(float4* __restrict__ p, long n4) {
    long i = (long)blockIdx.x * blockDim.x + threadIdx.x;
    long stride = (long)gridDim.x * blockDim.x;
    float4 z = make_float4(0.f, 0.f, 0.f, 0.f);
    for (; i < n4; i += stride) p[i] = z;
}
__global__ void scatter_add_kernel(const float4* __restrict__ src4, const int* __restrict__ idx,
                                   float* __restrict__ out, float* __restrict__ cnt, int E) {
    long t = (long)blockIdx.x * blockDim.x + threadIdx.x;
    long total = (long)E * 16;
    long stride = (long)gridDim.x * blockDim.x;
    for (; t < total; t += stride) {
        int e = (int)(t >> 4), c4 = (int)(t & 15);
        int n = idx[e];
        float4 v = src4[(long)e * 16 + c4];
        float* o = out + (long)n * 64 + c4 * 4;
        atomicAdd(o + 0, v.x); atomicAdd(o + 1, v.y);
        atomicAdd(o + 2, v.z); atomicAdd(o + 3, v.w);
        if (c4 == 0) atomicAdd(cnt + n, 1.0f);
    }
}
__global__ void divide_kernel(float4* __restrict__ out4, const float* __restrict__ cnt, int N) {
    long t = (long)blockIdx.x * blockDim.x + threadIdx.x;
    long total = (long)N * 16;
    long stride = (long)gridDim.x * blockDim.x;
    for (; t < total; t += stride) {
        int n = (int)(t >> 4);
        float inv = 1.0f / fmaxf(cnt[n], 1.0f);
        float4 v = out4[t];
        v.x *= inv; v.y *= inv; v.z *= inv; v.w *= inv;
        out4[t] = v;
    }
}

extern "C" void kernel_launch(void* const* d_in, const int* in_sizes, int n_in,
                              void* d_out, int out_size, void* d_ws, size_t ws_size,
                              hipStream_t stream) {
    const float* src = (const float*)d_in[0];
    const int*   idx = (const int*)d_in[1];
    float* out = (float*)d_out;

    const int E = in_sizes[1];           // 800000
    const int D = in_sizes[0] / E;       // 64
    const int N = out_size / D;          // 50000
    const int BLK = 256;

    // ws layout (u32 units): cnt[N] | ovf_cnt+list | slot[N*CAP]
    const size_t CNT_OFF  = 0;                                       // N
    const size_t OVF_OFF  = ((size_t)N + 63) & ~63ul;                // 1 + OVF_MAX
    const size_t SLOT_OFF = (OVF_OFF + 1 + OVF_MAX + 127) & ~127ul;  // N*CAP
    const size_t NEED = (SLOT_OFF + (size_t)N * CAP) * 4;

    if (ws_size >= NEED) {
        u32* W    = (u32*)d_ws;
        u32* cnt  = W + CNT_OFF;
        u32* ovf  = W + OVF_OFF;
        u32* slot = W + SLOT_OFF;

        // try the fused cooperative kernel first
        bool done = false;
        int maxB = 0;
        hipError_t rc0 = hipOccupancyMaxActiveBlocksPerMultiprocessor(
            &maxB, fused_scatter_mean_kernel, BLK, 0);
        if (rc0 == hipSuccess && maxB > 0) {
            int grid = maxB * 256;        // 256 CUs on MI355X
            if (grid > 1024) grid = 1024;
            const float4* src4 = (const float4*)src;
            float4* out4 = (float4*)out;
            int E_ = E, N_ = N;
            void* args[] = { (void*)&src4, (void*)&idx, (void*)&cnt, (void*)&ovf,
                             (void*)&slot, (void*)&out4, (void*)&E_, (void*)&N_ };
            hipError_t rc = hipLaunchCooperativeKernel(
                (const void*)fused_scatter_mean_kernel,
                dim3(grid), dim3(BLK), args, 0, stream);
            if (rc == hipSuccess) done = true;
        }

        if (!done) {
            // separate-kernel slot pipeline (round-7)
            {
                int span = (int)(OVF_OFF - CNT_OFF) + 1;
                int grid = (span + BLK - 1) / BLK;
                zero_u32_kernel<<<grid, BLK, 0, stream>>>(cnt, span);
            }
            {
                int grid = (E + BLK - 1) / BLK;
                slot_scatter_kernel<<<grid, BLK, 0, stream>>>(idx, cnt, slot, ovf, E);
            }
            {
                int segs_per_blk = BLK / 64;
                int grid = (N + segs_per_blk - 1) / segs_per_blk;
                gather_mean_kernel<<<grid, BLK, 0, stream>>>((const float4*)src, slot, cnt,
                                                             (float4*)out, N);
            }
            ovf_fix_kernel<<<1, 256, 0, stream>>>(src, idx, cnt, ovf, out);
        }
    } else {
        // small-ws fallback: atomic scatter-add
        float* cnt = (float*)d_ws;
        {
            long n4 = (long)out_size / 4;
            int grid = (int)((n4 + BLK - 1) / BLK); if (grid > 2048) grid = 2048;
            zero_f4_kernel<<<grid, BLK, 0, stream>>>((float4*)out, n4);
        }
        {
            long n4 = (long)N / 4;
            int grid = (int)((n4 + BLK - 1) / BLK); if (grid > 2048) grid = 2048;
            zero_f4_kernel<<<grid, BLK, 0, stream>>>((float4*)cnt, n4);
        }
        {
            long total = (long)E * 16;
            int grid = (int)((total + BLK - 1) / BLK); if (grid > 2048) grid = 2048;
            scatter_add_kernel<<<grid, BLK, 0, stream>>>((const float4*)src, idx, out, cnt, E);
        }
        {
            long total = (long)N * 16;
            int grid = (int)((total + BLK - 1) / BLK); if (grid > 2048) grid = 2048;
            divide_kernel<<<grid, BLK, 0, stream>>>((float4*)out, cnt, N);
        }
    }
}